// Round 13
// baseline (1134.216 us; speedup 1.0000x reference)
//
#include <hip/hip_runtime.h>

#define SEQ   2048
#define BATCH 4096
#define HID   6
#define BLK   128   // 2 waves/block; 8 element-pairs = 16 elements/block

typedef float v2f __attribute__((ext_vector_type(2)));
typedef unsigned u2 __attribute__((ext_vector_type(2)));

// ---- fast HW math ----
__device__ __forceinline__ float fexp2(float a) {
#if __has_builtin(__builtin_amdgcn_exp2f)
  return __builtin_amdgcn_exp2f(a);
#else
  float r; asm("v_exp_f32 %0, %1" : "=v"(r) : "v"(a)); return r;
#endif
}
__device__ __forceinline__ float frcp(float a) {
#if __has_builtin(__builtin_amdgcn_rcpf)
  return __builtin_amdgcn_rcpf(a);
#else
  float r; asm("v_rcp_f32 %0, %1" : "=v"(r) : "v"(a)); return r;
#endif
}
__device__ __forceinline__ v2f exp2v(v2f a) { return v2f{fexp2(a.x), fexp2(a.y)}; }
__device__ __forceinline__ v2f rcpv(v2f a)  { return v2f{frcp(a.x), frcp(a.y)}; }
__device__ __forceinline__ v2f sp(float w)  { return v2f{w, w}; }   // splat

// ---- DPP cross-lane (VALU pipe, ~4cy; R8-validated xor-gather primitives) ----
template <int CTRL>
__device__ __forceinline__ float dppf(float v) {
  int r = __builtin_amdgcn_update_dpp(0, __builtin_bit_cast(int, v), CTRL, 0xF, 0xF, true);
  return __builtin_bit_cast(float, r);
}
// 0xB1 quad_perm[1,0,3,2]=xor1; 0x4E quad_perm[2,3,0,1]=xor2; 0x141 row_half_mirror=xor7

// lane l <-> l^32 via v_permlane32_swap_b32 (polarity validated R7/R10 PASS)
__device__ __forceinline__ float xhalf(float v, bool hi) {
#if __has_builtin(__builtin_amdgcn_permlane32_swap)
  u2 r = __builtin_amdgcn_permlane32_swap(__builtin_bit_cast(unsigned, v),
                                          __builtin_bit_cast(unsigned, v), false, false);
  return __builtin_bit_cast(float, hi ? r.x : r.y);
#else
  unsigned d = __builtin_bit_cast(unsigned, v), s = d;
  asm volatile("v_permlane32_swap_b32 %0, %1" : "+v"(d), "+v"(s));
  return __builtin_bit_cast(float, hi ? d : s);
#endif
}

__global__ __launch_bounds__(BLK, 1) void lstm2_kernel(
    const float* __restrict__ x,
    const float* __restrict__ Wih0, const float* __restrict__ Whh0,
    const float* __restrict__ bih0, const float* __restrict__ bhh0,
    const float* __restrict__ Wih1, const float* __restrict__ Whh1,
    const float* __restrict__ bih1, const float* __restrict__ bhh1,
    const float* __restrict__ W2,   const float* __restrict__ b2,
    float* __restrict__ out)
{
  __shared__ float obuf[64][16];   // staged output rows (16 elems/block)

  const int tid = threadIdx.x;
  const int wib = tid >> 6;            // wave in block 0..1
  const int l6  = tid & 63;
  const bool hi = l6 >= 32;            // layer: lo lanes = L0, hi lanes = L1
  const int pp  = (l6 >> 3) & 3;       // element-PAIR within wave 0..3
  const int u   = l6 & 7;              // unit 0..7 (6,7 pads)
  const int uu  = (u < HID) ? u : (HID - 1);
  const int gp  = wib * 4 + pp;        // pair within block 0..7
  // elements e0 = blockIdx.x*16 + gp*2, e1 = e0+1; lane v2f components = {e0, e1}

  // Scalar weights, XOR-RELATIVE unit order (R8-validated vs 7-DPP flat gather):
  // slot k multiplies gathered value h[u^k]; pads (u^k>=HID) get weight 0.
  float WR[4][8], WI[4][8], w2s[8], BS[4];
#pragma unroll
  for (int q = 0; q < 4; ++q) {
    const int rq = q * HID + uu;
    const float Kq = (q == 2) ? -2.8853900817779268f : -1.4426950408889634f;
#pragma unroll
    for (int k = 0; k < 8; ++k) {
      const int kk = u ^ k;
      const bool ok = (kk < HID);
      WR[q][k] = ok ? Kq * (hi ? Whh1[rq * HID + kk] : Whh0[rq * HID + kk]) : 0.f;
      WI[q][k] = (hi && ok) ? Kq * Wih1[rq * HID + kk] : 0.f;
    }
    if (!hi) {   // L0 input dot: slots 0,1 carry the x-pair weights
      WI[q][0] = Kq * Wih0[rq * 2 + 0];
      WI[q][1] = Kq * Wih0[rq * 2 + 1];
    }
    BS[q] = Kq * ((hi ? bih1[rq] : bih0[rq]) + (hi ? bhh1[rq] : bhh0[rq]));
  }
#pragma unroll
  for (int k = 0; k < 8; ++k) {
    const int kk = u ^ k;
    w2s[k] = (kk < HID) ? W2[kk] : 0.f;
  }
  const float bout = b2[0];
  const v2f ONE = v2f{1.f, 1.f};
  const v2f KTv = v2f{2.8853900817779268f, 2.8853900817779268f};

  v2f h = v2f{0.f, 0.f}, c = v2f{0.f, 0.f};   // own-layer state for both elements

  // flat xor-gather, per component (14 DPP, depth 2): g[k] = {h_e0[u^k], h_e1[u^k]}
  auto gathc = [&](v2f hv, v2f (&g)[8]) {
    float hx = hv.x, hy = hv.y;
    float tx1 = dppf<0xB1>(hx),  ty1 = dppf<0xB1>(hy);    // xor1
    float tx2 = dppf<0x4E>(hx),  ty2 = dppf<0x4E>(hy);    // xor2
    float tx3 = dppf<0x4E>(tx1), ty3 = dppf<0x4E>(ty1);   // xor3
    float mx  = dppf<0x141>(hx), my  = dppf<0x141>(hy);   // xor7
    float mx1 = dppf<0xB1>(mx),  my1 = dppf<0xB1>(my);    // xor6
    float mx2 = dppf<0x4E>(mx),  my2 = dppf<0x4E>(my);    // xor5
    float mx3 = dppf<0x4E>(mx1), my3 = dppf<0x4E>(my1);   // xor4
    g[0] = v2f{hx,  hy};  g[1] = v2f{tx1, ty1};
    g[2] = v2f{tx2, ty2}; g[3] = v2f{tx3, ty3};
    g[4] = v2f{mx3, my3}; g[5] = v2f{mx2, my2};
    g[6] = v2f{mx1, my1}; g[7] = v2f{mx,  my};
  };

  // one fused step: lo = L0 cell (x, h0-rec); hi = L1 cell (h0 via permlane, h1-rec).
  // ov = out-dot of hi's own-gather (= h1[t-2] row), per element.
  auto step = [&](v2f xp0, v2f xp1, v2f& ov) {
    v2f g2[8]; gathc(h, g2);
    v2f g1[8];
#pragma unroll
    for (int k = 0; k < 8; ++k)
      g1[k] = v2f{xhalf(g2[k].x, hi), xhalf(g2[k].y, hi)};
    v2f in0 = hi ? g1[0] : xp0;
    v2f in1 = hi ? g1[1] : xp1;

    v2f a[4];
#pragma unroll
    for (int q = 0; q < 4; ++q) {
      v2f acc = sp(BS[q]);
      acc = __builtin_elementwise_fma(sp(WI[q][0]), in0, acc);
      acc = __builtin_elementwise_fma(sp(WI[q][1]), in1, acc);
#pragma unroll
      for (int k = 2; k < 8; ++k)
        acc = __builtin_elementwise_fma(sp(WI[q][k]), g1[k], acc);
#pragma unroll
      for (int k = 0; k < 8; ++k)
        acc = __builtin_elementwise_fma(sp(WR[q][k]), g2[k], acc);
      a[q] = acc;
    }
    v2f ao = sp(bout);
#pragma unroll
    for (int k = 0; k < 8; ++k)
      ao = __builtin_elementwise_fma(sp(w2s[k]), g2[k], ao);
    ov = ao;

    // gates per element (components), pre-scaled: sigma = rcp(1+exp2(a))
    v2f i_ = rcpv(ONE + exp2v(a[0]));
    v2f f_ = rcpv(ONE + exp2v(a[1]));
    v2f g_ = __builtin_elementwise_fma(sp(2.f), rcpv(ONE + exp2v(a[2])), sp(-1.f));
    v2f o_ = rcpv(ONE + exp2v(a[3]));
    c = __builtin_elementwise_fma(f_, c, i_ * g_);
    v2f th = __builtin_elementwise_fma(sp(-2.f), rcpv(ONE + exp2v(c * KTv)), ONE);
    h = o_ * th;
  };

  // flush: 64 rows x 16 elems; 128 threads x 2 float4 = full 64B lines per row
  auto flush = [&](int rbase) {
    const int row = tid >> 1, half = (tid & 1) * 8;
    float4 v0 = *(const float4*)&obuf[row][half];
    float4 v1 = *(const float4*)&obuf[row][half + 4];
    float* dst = &out[(size_t)(rbase + row) * BATCH + blockIdx.x * 16 + half];
    *(float4*)dst = v0;
    *(float4*)(dst + 4) = v1;
  };

  // x as float4 per pair: idx(t) = t*2048 + blockIdx.x*8 + gp -> {x_e0_0, x_e0_1, x_e1_0, x_e1_1}
  const float4* x4 = (const float4*)x;
  const size_t xidx = (size_t)blockIdx.x * 8 + gp;
  float4 xc4 = x4[xidx], xn4 = x4[(size_t)1 * 2048 + xidx];

  // t = 0 peel: lo computes h0[0]; hi result is pre-sequence garbage -> reset
  {
    v2f ov;
    step(v2f{xc4.x, xc4.z}, v2f{xc4.y, xc4.w}, ov);
    if (hi) { h = v2f{0.f, 0.f}; c = v2f{0.f, 0.f}; }
    xc4 = xn4;
    xn4 = x4[(size_t)2 * 2048 + xidx];
  }

  // iteration t: lo -> h0[t]; hi -> h1[t-1]; out row t-2 from hi's own-gather
#pragma unroll 1
  for (int t = 1; t < SEQ; ++t) {
    const int tn = (t + 2 < SEQ) ? t + 2 : SEQ - 1;
    float4 xf4 = x4[(size_t)tn * 2048 + xidx];

    v2f ov;
    step(v2f{xc4.x, xc4.z}, v2f{xc4.y, xc4.w}, ov);

    if (t >= 2) {
      const int r = t - 2;
      if (hi && u == 0) *(v2f*)&obuf[r & 63][gp * 2] = ov;
      if ((r & 63) == 63) {          // uniform branch, once per 64 steps
        __syncthreads();
        flush(r - 63);
        __syncthreads();
      }
    }
    xc4 = xn4; xn4 = xf4;
  }

  // epilogue: one more fused step -> h1[S-1] + out row S-2; final gather -> row S-1
  {
    v2f ov;
    step(v2f{xc4.x, xc4.z}, v2f{xc4.y, xc4.w}, ov);
    if (hi && u == 0) *(v2f*)&obuf[62][gp * 2] = ov;
    v2f g2[8]; gathc(h, g2);
    v2f ao = sp(bout);
#pragma unroll
    for (int k = 0; k < 8; ++k)
      ao = __builtin_elementwise_fma(sp(w2s[k]), g2[k], ao);
    if (hi && u == 0) *(v2f*)&obuf[63][gp * 2] = ao;
    __syncthreads();
    flush(SEQ - 64);
  }
}

extern "C" void kernel_launch(void* const* d_in, const int* in_sizes, int n_in,
                              void* d_out, int out_size, void* d_ws, size_t ws_size,
                              hipStream_t stream) {
  const float* x    = (const float*)d_in[0];
  const float* Wih0 = (const float*)d_in[1];
  const float* Whh0 = (const float*)d_in[2];
  const float* bih0 = (const float*)d_in[3];
  const float* bhh0 = (const float*)d_in[4];
  const float* Wih1 = (const float*)d_in[5];
  const float* Whh1 = (const float*)d_in[6];
  const float* bih1 = (const float*)d_in[7];
  const float* bhh1 = (const float*)d_in[8];
  const float* W2   = (const float*)d_in[9];
  const float* b2   = (const float*)d_in[10];
  float* out = (float*)d_out;

  dim3 grid(BATCH / 16);   // 256 blocks x 2 waves = 512 waves (8 elems/wave)
  dim3 block(BLK);
  hipLaunchKernelGGL(lstm2_kernel, grid, block, 0, stream,
                     x, Wih0, Whh0, bih0, bhh0, Wih1, Whh1, bih1, bhh1, W2, b2, out);
}

// Round 14
// 681.178 us; speedup vs baseline: 1.6651x; 1.6651x over previous
//
#include <hip/hip_runtime.h>

#define SEQ   2048
#define BATCH 4096
#define HID   6
#define BLK   256   // 4 waves/block; 16 elements/block; 256 blocks -> 1 block/CU

typedef float v2f __attribute__((ext_vector_type(2)));
typedef unsigned u2 __attribute__((ext_vector_type(2)));

// ---- fast HW math ----
__device__ __forceinline__ float fexp2(float a) {
#if __has_builtin(__builtin_amdgcn_exp2f)
  return __builtin_amdgcn_exp2f(a);
#else
  float r; asm("v_exp_f32 %0, %1" : "=v"(r) : "v"(a)); return r;
#endif
}
__device__ __forceinline__ float frcp(float a) {
#if __has_builtin(__builtin_amdgcn_rcpf)
  return __builtin_amdgcn_rcpf(a);
#else
  float r; asm("v_rcp_f32 %0, %1" : "=v"(r) : "v"(a)); return r;
#endif
}

// ---- ds_swizzle broadcast of lane (8-group base + J) to the 8-group (R7-validated)
// BitMode offset = (xor<<10)|(or<<5)|and ; and=0x18 keeps element bits [4:3].
template <int OFF>
__device__ __forceinline__ float swzf(float v) {
  int r = __builtin_amdgcn_ds_swizzle(__builtin_bit_cast(int, v), OFF);
  return __builtin_bit_cast(float, r);
}
#define BC0 0x18
#define BC1 0x38
#define BC2 0x58
#define BC3 0x78
#define BC4 0x98
#define BC5 0xB8

// lane l <-> l^32 exchange via v_permlane32_swap_b32 (polarity validated R7/R10 PASS:
// lanes >=32 take r.x, lanes <32 take r.y).
__device__ __forceinline__ float xhalf(float v, bool hi) {
#if __has_builtin(__builtin_amdgcn_permlane32_swap)
  u2 r = __builtin_amdgcn_permlane32_swap(__builtin_bit_cast(unsigned, v),
                                          __builtin_bit_cast(unsigned, v), false, false);
  return __builtin_bit_cast(float, hi ? r.x : r.y);
#else
  unsigned d = __builtin_bit_cast(unsigned, v), s = d;
  asm volatile("v_permlane32_swap_b32 %0, %1" : "+v"(d), "+v"(s));
  return __builtin_bit_cast(float, hi ? d : s);
#endif
}

__global__ __launch_bounds__(BLK, 1) void lstm2_kernel(
    const float* __restrict__ x,
    const float* __restrict__ Wih0, const float* __restrict__ Whh0,
    const float* __restrict__ bih0, const float* __restrict__ bhh0,
    const float* __restrict__ Wih1, const float* __restrict__ Whh1,
    const float* __restrict__ bih1, const float* __restrict__ bhh1,
    const float* __restrict__ W2,   const float* __restrict__ b2,
    float* __restrict__ out)
{
  __shared__ float obuf[64][16];   // staged output rows; bulk-flushed every 64 steps

  const int tid = threadIdx.x;
  const int wib = tid >> 6;            // wave in block 0..3
  const int l6  = tid & 63;
  const bool hi = l6 >= 32;            // false: layer-0 lanes, true: layer-1 lanes
  const int j   = l6 & 31;
  const int el  = j >> 3;              // element within wave 0..3
  const int u   = j & 7;               // unit 0..7 (6,7 pads)
  const int uu  = (u < HID) ? u : (HID - 1);
  const int elb = wib * 4 + el;        // element within block 0..15
  const int b   = blockIdx.x * 16 + elb;

  // Per-row constants, rows q = 0..3 (i,f,g,o); gate scale K folded into
  // weights+bias. ABSOLUTE pair order (R7-validated): slot k = {W[2k], W[2k+1]}.
  v2f WA[4][3], WB[4][3];
  float BS[4];
#pragma unroll
  for (int q = 0; q < 4; ++q) {
    const int rq = q * HID + uu;
    const float Kq = (q == 2) ? -2.8853900817779268f : -1.4426950408889634f;
    if (!hi) {
      WA[q][0] = v2f{Kq * Wih0[rq * 2 + 0], Kq * Wih0[rq * 2 + 1]};
      WA[q][1] = v2f{0.f, 0.f};
      WA[q][2] = v2f{0.f, 0.f};
#pragma unroll
      for (int k = 0; k < 3; ++k)
        WB[q][k] = v2f{Kq * Whh0[rq * HID + 2 * k], Kq * Whh0[rq * HID + 2 * k + 1]};
      BS[q] = Kq * (bih0[rq] + bhh0[rq]);
    } else {
#pragma unroll
      for (int k = 0; k < 3; ++k) {
        WA[q][k] = v2f{Kq * Wih1[rq * HID + 2 * k], Kq * Wih1[rq * HID + 2 * k + 1]};
        WB[q][k] = v2f{Kq * Whh1[rq * HID + 2 * k], Kq * Whh1[rq * HID + 2 * k + 1]};
      }
      BS[q] = Kq * (bih1[rq] + bhh1[rq]);
    }
  }
  const v2f w2p0 = v2f{W2[0], W2[1]}, w2p1 = v2f{W2[2], W2[3]}, w2p2 = v2f{W2[4], W2[5]};
  const float bout = b2[0];
  const float KT = 2.8853900817779268f;   // tanh(c) = 1 - 2*rcp(1+exp2(KT*c))

  float h = 0.f, c = 0.f;   // own-layer state: lo = (h0,c0), hi = (h1,c1)

  // absolute-order gather of own-group h (lanes 0..5 real) into 3 pairs
  auto gath = [&](float hv, v2f (&g)[3]) {
    g[0] = v2f{swzf<BC0>(hv), swzf<BC1>(hv)};
    g[1] = v2f{swzf<BC2>(hv), swzf<BC3>(hv)};
    g[2] = v2f{swzf<BC4>(hv), swzf<BC5>(hv)};
  };

  // one fused step: lo computes L0 cell (x, h0-rec), hi computes L1 cell.
  // SINGLE LDS round-trip per step: L1's input gather g1 = permlane32 of the
  // ALREADY-GATHERED g2 pairs (VALU, ~16cy) instead of a second swizzle-gather
  // (~120-150cy LDS latency on the recurrence chain). R10/R11/R13-validated.
  auto step = [&](v2f xc, float& ov) {
    v2f g2[3]; gath(h, g2);                 // own-layer recurrence input
    v2f g1[3];
    g1[0] = v2f{xhalf(g2[0].x, hi), xhalf(g2[0].y, hi)};
    g1[1] = v2f{xhalf(g2[1].x, hi), xhalf(g2[1].y, hi)};
    g1[2] = v2f{xhalf(g2[2].x, hi), xhalf(g2[2].y, hi)};
    v2f v10 = hi ? g1[0] : xc;              // lo: x pair (WA[..][1,2]=0)

    float a[4];
#pragma unroll
    for (int q = 0; q < 4; ++q) {
      v2f accA = __builtin_elementwise_fma(WA[q][0], v10, v2f{BS[q], 0.f});
      accA = __builtin_elementwise_fma(WA[q][1], g1[1], accA);
      accA = __builtin_elementwise_fma(WA[q][2], g1[2], accA);
      v2f accB = WB[q][0] * g2[0];
      accB = __builtin_elementwise_fma(WB[q][1], g2[1], accB);
      accB = __builtin_elementwise_fma(WB[q][2], g2[2], accB);
      v2f acc = accA + accB;
      a[q] = acc.x + acc.y;
    }
    // output row dot from hi's g2 = h1g[t-2]
    v2f ao = __builtin_elementwise_fma(w2p0, g2[0],
             __builtin_elementwise_fma(w2p1, g2[1],
             __builtin_elementwise_fma(w2p2, g2[2], v2f{bout, 0.f})));
    ov = ao.x + ao.y;

    // gates (a pre-scaled): sigma = rcp(1+exp2(a)); g-gate = 2*sigma-1
    float i_ = frcp(1.f + fexp2(a[0]));
    float f_ = frcp(1.f + fexp2(a[1]));
    float g_ = fmaf(2.f, frcp(1.f + fexp2(a[2])), -1.f);
    float o_ = frcp(1.f + fexp2(a[3]));
    c = fmaf(f_, c, i_ * g_);
    float th = fmaf(-2.f, frcp(1.f + fexp2(c * KT)), 1.f);
    h = o_ * th;
  };

  // bulk flush: 64 rows x 16 elements as float4 per thread (full 64B lines)
  auto flush = [&](int rbase) {
    const int r = tid >> 2, jj = (tid & 3) * 4;
    float4 vv = *(const float4*)&obuf[r][jj];
    *(float4*)&out[(size_t)(rbase + r) * BATCH + blockIdx.x * 16 + jj] = vv;
  };

  const v2f* x2 = (const v2f*)x;
  // x prefetch queue, depth 4 (R7-validated); invariant at entry t: (xc..xn3)=x[t..t+3]
  v2f xc  = x2[(size_t)0 * BATCH + b];
  v2f xn1 = x2[(size_t)1 * BATCH + b];
  v2f xn2 = x2[(size_t)2 * BATCH + b];
  v2f xn3 = x2[(size_t)3 * BATCH + b];

  // t = 0 peel: lo computes h0[0]; hi's result is pre-sequence garbage -> reset
  {
    float ov;
    step(xc, ov);
    if (hi) { h = 0.f; c = 0.f; }
    v2f xf = x2[(size_t)4 * BATCH + b];
    xc = xn1; xn1 = xn2; xn2 = xn3; xn3 = xf;
  }

  // iteration t: lo -> h0[t] (x[t], h0[t-1]); hi -> h1[t-1] (h0[t-1], h1[t-2]);
  // out row t-2 from hi's recurrence gather.
#pragma unroll 1
  for (int t = 1; t < SEQ; ++t) {
    int tf = t + 4; tf = (tf < SEQ) ? tf : (SEQ - 1);
    v2f xf = x2[(size_t)tf * BATCH + b];

    float ov;
    step(xc, ov);

    if (t >= 2) {
      const int r = t - 2;
      if (hi && u == 0) obuf[r & 63][elb] = ov;
      if ((r & 63) == 63) {          // uniform branch, once per 64 steps
        __syncthreads();
        flush(r - 63);
        __syncthreads();
      }
    }
    xc = xn1; xn1 = xn2; xn2 = xn3; xn3 = xf;
  }

  // epilogue: one more fused step -> h1[S-1] + out row S-2; final gather -> row S-1
  {
    float ov;
    step(xc, ov);
    if (hi && u == 0) obuf[62][elb] = ov;
    v2f g2[3]; gath(h, g2);
    v2f ao = __builtin_elementwise_fma(w2p0, g2[0],
             __builtin_elementwise_fma(w2p1, g2[1],
             __builtin_elementwise_fma(w2p2, g2[2], v2f{bout, 0.f})));
    if (hi && u == 0) obuf[63][elb] = ao.x + ao.y;
    __syncthreads();
    flush(SEQ - 64);
  }
}

extern "C" void kernel_launch(void* const* d_in, const int* in_sizes, int n_in,
                              void* d_out, int out_size, void* d_ws, size_t ws_size,
                              hipStream_t stream) {
  const float* x    = (const float*)d_in[0];
  const float* Wih0 = (const float*)d_in[1];
  const float* Whh0 = (const float*)d_in[2];
  const float* bih0 = (const float*)d_in[3];
  const float* bhh0 = (const float*)d_in[4];
  const float* Wih1 = (const float*)d_in[5];
  const float* Whh1 = (const float*)d_in[6];
  const float* bih1 = (const float*)d_in[7];
  const float* bhh1 = (const float*)d_in[8];
  const float* W2   = (const float*)d_in[9];
  const float* b2   = (const float*)d_in[10];
  float* out = (float*)d_out;

  dim3 grid(BATCH / 16);   // 256 blocks x 4 waves = 1024 waves = 1 wave/SIMD
  dim3 block(BLK);
  hipLaunchKernelGGL(lstm2_kernel, grid, block, 0, stream,
                     x, Wih0, Whh0, bih0, bhh0, Wih1, Whh1, bih1, bhh1, W2, b2, out);
}